// Round 1
// baseline (2341.866 us; speedup 1.0000x reference)
//
#include <hip/hip_runtime.h>

// SpikingLinearLayer: 20-step LIF over [512 batch, 2048 out] driven by
// binary (10% dense) input spikes x[20,512,2048] through W[2048,2048].
//
// Strategy:
//  - I-recurrence is linear & spike-independent -> all 20 GEMMs computed
//    in one fused pass, V-scan done in registers at the end.
//  - x is {0,1}: C[t,b,o] = sum of W rows at active i -> fp64 ADDS only
//    (4.3G adds), gathered from an LDS-staged transposed W slab.
//  - fp64 everywhere: binary-spike output means any accumulation noise
//    > ~1e-7 near threshold flips a spike (absmax 1.0). fp64 matches a
//    float64 numpy reference to ~1e-13.

#define STEPS  20
#define BATCH  512
#define DIM    2048
#define B_TILE 4
#define O_TILE 256            // block size, thread = one output neuron
#define KT     64             // k-slab
#define O_PAD  257            // LDS row pad (bank-conflict-free)
#define NPAIRS (STEPS * B_TILE)   // 80 (t,b) pairs per block
#define LIST_CAP 32               // active-index slots per pair per slab
#define PAD_OFF  (KT * O_PAD)     // offset of the zero row (pad target)

__global__ __launch_bounds__(O_TILE)
void snn_lif_kernel(const float* __restrict__ x,
                    const float* __restrict__ W,
                    float* __restrict__ out)
{
    __shared__ float wlds[(KT + 1) * O_PAD];                    // 66.8 KB
    __shared__ __align__(16) unsigned short lists[NPAIRS * LIST_CAP]; // 5 KB
    __shared__ int counts[NPAIRS];

    const int tid  = threadIdx.x;
    const int lane = tid & 63;
    const int wv   = tid >> 6;                 // wave id 0..3 -> batch lane
    const int o_blk = blockIdx.x & 7;          // DIM / O_TILE = 8 (o fastest:
    const int b_blk = blockIdx.x >> 3;         //  same W-strip -> same XCD L2)
    const int o  = o_blk * O_TILE + tid;
    const int b0 = b_blk * B_TILE;

    double acc[NPAIRS];                        // C[t][b] accumulators (fp64)
#pragma unroll
    for (int p = 0; p < NPAIRS; ++p) acc[p] = 0.0;

    // zero row KT: pad indices land here -> += 0.0
    for (int i = tid; i < O_PAD; i += O_TILE) wlds[KT * O_PAD + i] = 0.0f;

    for (int kt = 0; kt < DIM / KT; ++kt) {
        const int k0 = kt * KT;
        __syncthreads();  // previous slab's compute done before restage

        // ---- stage W slab transposed: wlds[k][o_local] = W[o_glob][k0+k]
        {
            const int kk = (tid & 15) * 4;     // 16 float4 columns
            const int ob = tid >> 4;           // 16 rows per pass
#pragma unroll
            for (int it = 0; it < 16; ++it) {
                const int o_off = ob + it * 16;
                const float4 v = *reinterpret_cast<const float4*>(
                    W + (size_t)(o_blk * O_TILE + o_off) * DIM + k0 + kk);
                wlds[(kk + 0) * O_PAD + o_off] = v.x;
                wlds[(kk + 1) * O_PAD + o_off] = v.y;
                wlds[(kk + 2) * O_PAD + o_off] = v.z;
                wlds[(kk + 3) * O_PAD + o_off] = v.w;
            }
        }

        // ---- build active-index lists (ballot + prefix-popcount compact).
        // Entries are pre-scaled LDS word offsets k*O_PAD; inactive lanes
        // fill the tail slots with PAD_OFF (zero row) so chunks need no
        // tail masking.
        {
            const unsigned long long below = (1ull << lane) - 1ull;
#pragma unroll 1
            for (int j = 0; j < STEPS; ++j) {
                const int p = j * B_TILE + wv;
                const float xv =
                    x[((size_t)j * BATCH + (b0 + wv)) * DIM + k0 + lane];
                const bool act = (xv != 0.0f);
                const unsigned long long m = __ballot(act);
                const int c = __popcll(m);
                const int pos = act ? __popcll(m & below)
                                    : c + __popcll((~m) & below);
                if (pos < LIST_CAP)
                    lists[p * LIST_CAP + pos] =
                        act ? (unsigned short)(lane * O_PAD)
                            : (unsigned short)PAD_OFF;
                if (lane == 0) counts[p] = c;
            }
        }
        __syncthreads();

        // ---- sparse fp64 accumulate: 8 gathered adds per chunk
#pragma unroll
        for (int p = 0; p < NPAIRS; ++p) {
            int c = counts[p];
            c = __builtin_amdgcn_readfirstlane(c);
            if (c > LIST_CAP) c = LIST_CAP;   // (P ~ 1e-15, safety)
            const int nch = (c + 7) >> 3;
            for (int ch = 0; ch < nch; ++ch) {
                const uint4 iv = *reinterpret_cast<const uint4*>(
                    lists + p * LIST_CAP + ch * 8);
                const int i0 = iv.x & 0xFFFF, i1 = iv.x >> 16;
                const int i2 = iv.y & 0xFFFF, i3 = iv.y >> 16;
                const int i4 = iv.z & 0xFFFF, i5 = iv.z >> 16;
                const int i6 = iv.w & 0xFFFF, i7 = iv.w >> 16;
                acc[p] += (double)wlds[i0 + tid];
                acc[p] += (double)wlds[i1 + tid];
                acc[p] += (double)wlds[i2 + tid];
                acc[p] += (double)wlds[i3 + tid];
                acc[p] += (double)wlds[i4 + tid];
                acc[p] += (double)wlds[i5 + tid];
                acc[p] += (double)wlds[i6 + tid];
                acc[p] += (double)wlds[i7 + tid];
            }
        }
    }

    // ---- LIF scan (fp64, matches reference op order) + spike emit
    const double A_M = 1.0 - 1.0 / 20.0;   // membrane decay 0.95
    const double DTM = 1.0 / 20.0;         // 0.05
    const double A_S = 1.0 - 1.0 / 5.0;    // synaptic decay 0.8
#pragma unroll
    for (int bi = 0; bi < B_TILE; ++bi) {
        double I = 0.0, V = 0.0;
#pragma unroll
        for (int t = 0; t < STEPS; ++t) {
            V = A_M * V + DTM * I;
            float s = 0.0f;
            if (V >= 1.0) { s = 1.0f; V = 0.0; }   // spike + reset-to-zero
            out[((size_t)t * BATCH + (b0 + bi)) * DIM + o] = s;
            I = A_S * I + acc[t * B_TILE + bi];    // add x_t @ W.T
        }
    }
}

extern "C" void kernel_launch(void* const* d_in, const int* in_sizes, int n_in,
                              void* d_out, int out_size, void* d_ws, size_t ws_size,
                              hipStream_t stream) {
    const float* x = (const float*)d_in[0];   // [20, 512, 2048] spikes
    const float* W = (const float*)d_in[1];   // [2048, 2048]
    float* out = (float*)d_out;               // [20, 512, 2048]

    const int grid = (BATCH / B_TILE) * (DIM / O_TILE);  // 128 * 8 = 1024
    snn_lif_kernel<<<grid, O_TILE, 0, stream>>>(x, W, out);
}

// Round 2
// 1345.335 us; speedup vs baseline: 1.7407x; 1.7407x over previous
//
#include <hip/hip_runtime.h>

// SpikingLinearLayer: 20-step LIF over [512 batch, 2048 out] driven by
// binary (10% dense) input spikes x[20,512,2048] through W[2048,2048].
//
//  - I-recurrence is linear & spike-independent -> all 20 GEMMs fused,
//    V-scan in registers at the end.
//  - x is {0,1}: C[t,b,o] = sum of W rows at active i -> fp64 ADDS only,
//    gathered from an LDS-staged transposed W slab (fp64 needed: binary
//    spike output flips on ~1e-7 accumulation noise near threshold).
//  - R2: 512-thread blocks (16 waves/CU, was 8), thread owns outputs
//    {j, j+128} so the two gathers merge into one ds_read2_b32; pairs
//    split by batch across wave-pairs -> 40 fp64 accs/thread (was 80).

#define STEPS  20
#define BATCH  512
#define DIM    2048
#define B_TILE 4
#define O_TILE 256
#define NT     512
#define KT     64
#define O_PAD  257
#define NPAIRS (STEPS * B_TILE)   // 80 (t,b) pairs per block
#define LIST_CAP 32
#define PAD_OFF  (KT * O_PAD)     // zero row (pad target)

__global__ __launch_bounds__(NT, 4)
void snn_lif_kernel(const float* __restrict__ x,
                    const float* __restrict__ W,
                    float* __restrict__ out)
{
    __shared__ float wlds[(KT + 1) * O_PAD];                    // 66.8 KB
    __shared__ __align__(16) unsigned short lists[NPAIRS * LIST_CAP];
    __shared__ int counts[NPAIRS];

    const int tid  = threadIdx.x;
    const int lane = tid & 63;
    const int w    = tid >> 6;        // wave 0..7
    const int q    = w >> 1;          // batch lane 0..3 (pairs split by batch!)
    const int j    = tid & 127;       // base output; thread owns {j, j+128}
    const int o_blk = blockIdx.x & 7; // o fastest: W strip stays warm in L2
    const int b_blk = blockIdx.x >> 3;
    const int b0 = b_blk * B_TILE;

    double acc[STEPS][2];             // 40 fp64 accs (80 VGPRs)
#pragma unroll
    for (int t = 0; t < STEPS; ++t) { acc[t][0] = 0.0; acc[t][1] = 0.0; }

    // zero row KT: pad indices land here -> += 0.0
    for (int i = tid; i < O_PAD; i += NT) wlds[PAD_OFF + i] = 0.0f;

    for (int kt = 0; kt < DIM / KT; ++kt) {
        const int k0 = kt * KT;
        __syncthreads();  // previous slab's compute done before restage

        // ---- stage W slab transposed: wlds[k][o_local] = W[o_glob][k0+k]
        // (float4 coalesced global reads; scalar writes land 2 lanes/bank
        //  = conflict-free per m136)
        {
            const int kk = (tid & 15) * 4;     // 16 float4 columns
            const int ob = tid >> 4;           // 32 rows per pass
#pragma unroll
            for (int it = 0; it < 8; ++it) {
                const int o_off = ob + it * 32;
                const float4 v = *reinterpret_cast<const float4*>(
                    W + (size_t)(o_blk * O_TILE + o_off) * DIM + k0 + kk);
                wlds[(kk + 0) * O_PAD + o_off] = v.x;
                wlds[(kk + 1) * O_PAD + o_off] = v.y;
                wlds[(kk + 2) * O_PAD + o_off] = v.z;
                wlds[(kk + 3) * O_PAD + o_off] = v.w;
            }
        }

        // ---- build active-index lists (ballot + prefix-popcount compact).
        // Wave w covers batch q = w>>1, steps [(w&1)*10, +10). Entries are
        // pre-scaled LDS word offsets k*O_PAD; tail slots -> PAD_OFF.
        {
            const unsigned long long below = (1ull << lane) - 1ull;
            const int t0 = (w & 1) * 10;
#pragma unroll 1
            for (int jj = 0; jj < 10; ++jj) {
                const int t = t0 + jj;
                const int p = t * B_TILE + q;
                const float xv =
                    x[((size_t)t * BATCH + (b0 + q)) * DIM + k0 + lane];
                const bool act = (xv != 0.0f);
                const unsigned long long m = __ballot(act);
                const int c = __popcll(m);
                const int pos = act ? __popcll(m & below)
                                    : c + __popcll((~m) & below);
                if (pos < LIST_CAP)
                    lists[p * LIST_CAP + pos] =
                        act ? (unsigned short)(lane * O_PAD)
                            : (unsigned short)PAD_OFF;
                if (lane == 0) counts[p] = c;
            }
        }
        __syncthreads();

        // ---- sparse fp64 accumulate; both waves of group q process all
        // 20 pairs of batch q for their own 128 outputs. The paired loads
        // at dword offsets {0,128} merge into ds_read2_b32.
#pragma unroll
        for (int t = 0; t < STEPS; ++t) {
            const int p = t * B_TILE + q;
            int c = counts[p];
            c = __builtin_amdgcn_readfirstlane(c);
            if (c > LIST_CAP) c = LIST_CAP;
            const int nch = (c + 7) >> 3;
            for (int ch = 0; ch < nch; ++ch) {
                const uint4 iv = *reinterpret_cast<const uint4*>(
                    lists + p * LIST_CAP + ch * 8);
                const int i0 = iv.x & 0xFFFF, i1 = iv.x >> 16;
                const int i2 = iv.y & 0xFFFF, i3 = iv.y >> 16;
                const int i4 = iv.z & 0xFFFF, i5 = iv.z >> 16;
                const int i6 = iv.w & 0xFFFF, i7 = iv.w >> 16;
                const float* g0 = wlds + i0 + j;
                const float* g1 = wlds + i1 + j;
                const float* g2 = wlds + i2 + j;
                const float* g3 = wlds + i3 + j;
                const float* g4 = wlds + i4 + j;
                const float* g5 = wlds + i5 + j;
                const float* g6 = wlds + i6 + j;
                const float* g7 = wlds + i7 + j;
                acc[t][0] += (double)g0[0]; acc[t][1] += (double)g0[128];
                acc[t][0] += (double)g1[0]; acc[t][1] += (double)g1[128];
                acc[t][0] += (double)g2[0]; acc[t][1] += (double)g2[128];
                acc[t][0] += (double)g3[0]; acc[t][1] += (double)g3[128];
                acc[t][0] += (double)g4[0]; acc[t][1] += (double)g4[128];
                acc[t][0] += (double)g5[0]; acc[t][1] += (double)g5[128];
                acc[t][0] += (double)g6[0]; acc[t][1] += (double)g6[128];
                acc[t][0] += (double)g7[0]; acc[t][1] += (double)g7[128];
            }
        }
    }

    // ---- LIF scan (fp64, matches reference op order) + spike emit
    const double A_M = 1.0 - 1.0 / 20.0;   // 0.95
    const double DTM = 1.0 / 20.0;         // 0.05
    const double A_S = 1.0 - 1.0 / 5.0;    // 0.8
    {
        const int b = b0 + q;
        const size_t obase = (size_t)o_blk * O_TILE + j;
        double I0 = 0.0, V0 = 0.0, I1 = 0.0, V1 = 0.0;
#pragma unroll
        for (int t = 0; t < STEPS; ++t) {
            V0 = A_M * V0 + DTM * I0;
            V1 = A_M * V1 + DTM * I1;
            float s0 = 0.0f, s1 = 0.0f;
            if (V0 >= 1.0) { s0 = 1.0f; V0 = 0.0; }
            if (V1 >= 1.0) { s1 = 1.0f; V1 = 0.0; }
            float* op = out + ((size_t)t * BATCH + b) * DIM + obase;
            op[0]   = s0;
            op[128] = s1;
            I0 = A_S * I0 + acc[t][0];
            I1 = A_S * I1 + acc[t][1];
        }
    }
}

extern "C" void kernel_launch(void* const* d_in, const int* in_sizes, int n_in,
                              void* d_out, int out_size, void* d_ws, size_t ws_size,
                              hipStream_t stream) {
    const float* x = (const float*)d_in[0];   // [20, 512, 2048] spikes
    const float* W = (const float*)d_in[1];   // [2048, 2048]
    float* out = (float*)d_out;               // [20, 512, 2048]

    const int grid = (BATCH / B_TILE) * (DIM / O_TILE);  // 128 * 8 = 1024
    snn_lif_kernel<<<grid, NT, 0, stream>>>(x, W, out);
}

// Round 3
// 909.496 us; speedup vs baseline: 2.5749x; 1.4792x over previous
//
#include <hip/hip_runtime.h>

// SpikingLinearLayer: 20-step LIF over [512 batch, 2048 out] driven by
// binary (10% dense) input spikes x[20,512,2048] through W[2048,2048].
//
//  - I-recurrence is linear & spike-independent -> all 20 GEMMs fused,
//    V-scan in registers at the end (h-split with one LDS handoff).
//  - x is {0,1}: C[t,b,o] = sum of W rows at active i -> fp64 ADDS only,
//    gathered from an LDS-staged transposed W slab (fp64 needed: binary
//    spike output flips on ~1e-7 accumulation noise near threshold).
//  - R3: prefetch W/x into regs across the gather phase (no global
//    latency between barriers); exact-count gather (8-chunks + 4/2/1
//    wave-uniform tails) kills the +50% chunk-pad waste; B_TILE=2 with
//    step-halves per thread keeps accs at 40 VGPRs -> 4 waves/SIMD.

#define STEPS  20
#define BATCH  512
#define DIM    2048
#define B_TILE 2
#define O_TILE 256
#define NT     512
#define KT     64
#define O_PAD  257
#define NLIST  (STEPS * B_TILE)   // 40 lists per block
#define LIST_CAP 32

__global__ __launch_bounds__(NT, 4)
void snn_lif_kernel(const float* __restrict__ x,
                    const float* __restrict__ W,
                    float* __restrict__ out)
{
    __shared__ float wlds[KT * O_PAD];                      // 65.8 KB
    __shared__ __align__(16) unsigned short lists[NLIST * LIST_CAP];
    __shared__ int counts[NLIST];

    const int tid  = threadIdx.x;
    const int lane = tid & 63;
    const int w    = tid >> 6;     // wave 0..7
    const int g    = w >> 1;       // group 0..3 = (batch-local, step-half)
    const int bl   = g >> 1;       // batch local 0..1
    const int h    = g & 1;        // step half: t in [h*10, h*10+10)
    const int par  = w & 1;        // ballot parity within group
    const int j    = tid & 127;    // thread owns outputs {j, j+128}
    const int o_blk = blockIdx.x & 7;   // o fastest: W strip warm in L2
    const int b_blk = blockIdx.x >> 3;
    const int b = b_blk * B_TILE + bl;

    double acc[10][2];             // C[h*10+tt][b][{j,j+128}]
#pragma unroll
    for (int tt = 0; tt < 10; ++tt) { acc[tt][0] = 0.0; acc[tt][1] = 0.0; }

    // ---- prefetch state (regs held across the gather phase)
    const int kk = (tid & 15) * 4;         // float4 column
    const int ob = tid >> 4;               // 0..31
    const float* wbase = W + (size_t)(o_blk * O_TILE) * DIM;
    float4 wr[8];
    float  xr[5];

    {   // slab 0
        const int k0 = 0;
#pragma unroll
        for (int it = 0; it < 8; ++it)
            wr[it] = *reinterpret_cast<const float4*>(
                wbase + (size_t)(ob + it * 32) * DIM + k0 + kk);
#pragma unroll
        for (int jj = 0; jj < 5; ++jj) {
            const int t = h * 10 + par + 2 * jj;
            xr[jj] = x[((size_t)t * BATCH + b) * DIM + k0 + lane];
        }
    }

    const unsigned long long below = (1ull << lane) - 1ull;
    const char* gbase = (const char*)wlds + j * 4;

    for (int kt = 0; kt < DIM / KT; ++kt) {
        __syncthreads();   // gathers of slab kt-1 done

        // ---- stage W slab (from prefetched regs; transposed, padded)
#pragma unroll
        for (int it = 0; it < 8; ++it) {
            const int o_off = ob + it * 32;
            wlds[(kk + 0) * O_PAD + o_off] = wr[it].x;
            wlds[(kk + 1) * O_PAD + o_off] = wr[it].y;
            wlds[(kk + 2) * O_PAD + o_off] = wr[it].z;
            wlds[(kk + 3) * O_PAD + o_off] = wr[it].w;
        }

        // ---- build active lists from prefetched x (byte offsets)
#pragma unroll
        for (int jj = 0; jj < 5; ++jj) {
            const int t = h * 10 + par + 2 * jj;
            const int p = t * B_TILE + bl;
            const bool act = (xr[jj] != 0.0f);
            const unsigned long long m = __ballot(act);
            const int c = __popcll(m);
            if (act) {
                const int pos = __popcll(m & below);
                if (pos < LIST_CAP)
                    lists[p * LIST_CAP + pos] =
                        (unsigned short)(lane * (O_PAD * 4));
            }
            if (lane == 0) counts[p] = c;
        }
        __syncthreads();   // LDS ready

        // ---- issue next slab's prefetch (consumed after next barrier;
        //      latency hidden behind this slab's gather)
        if (kt + 1 < DIM / KT) {
            const int k0 = (kt + 1) * KT;
#pragma unroll
            for (int it = 0; it < 8; ++it)
                wr[it] = *reinterpret_cast<const float4*>(
                    wbase + (size_t)(ob + it * 32) * DIM + k0 + kk);
#pragma unroll
            for (int jj = 0; jj < 5; ++jj) {
                const int t = h * 10 + par + 2 * jj;
                xr[jj] = x[((size_t)t * BATCH + b) * DIM + k0 + lane];
            }
        }

        // ---- exact-count sparse fp64 accumulate (8-chunks + 4/2/1 tails,
        //      trip counts wave-uniform -> scalar branches)
#pragma unroll
        for (int tt = 0; tt < 10; ++tt) {
            const int p = (h * 10 + tt) * B_TILE + bl;
            int c = __builtin_amdgcn_readfirstlane(counts[p]);
            if (c > LIST_CAP) c = LIST_CAP;
            const unsigned short* lp = lists + p * LIST_CAP;

            auto DO1 = [&](int e) {
                const float lo = *reinterpret_cast<const float*>(gbase + e);
                const float hi = *reinterpret_cast<const float*>(gbase + e + 512);
                acc[tt][0] += (double)lo;   // {e,e+512} -> one ds_read2_b32
                acc[tt][1] += (double)hi;
            };

            int pos = 0;
            for (; pos + 8 <= c; pos += 8) {
                const uint4 iv = *reinterpret_cast<const uint4*>(lp + pos);
                DO1(iv.x & 0xFFFF); DO1(iv.x >> 16);
                DO1(iv.y & 0xFFFF); DO1(iv.y >> 16);
                DO1(iv.z & 0xFFFF); DO1(iv.z >> 16);
                DO1(iv.w & 0xFFFF); DO1(iv.w >> 16);
            }
            if (c & 4) {
                const uint2 iv = *reinterpret_cast<const uint2*>(lp + pos);
                DO1(iv.x & 0xFFFF); DO1(iv.x >> 16);
                DO1(iv.y & 0xFFFF); DO1(iv.y >> 16);
                pos += 4;
            }
            if (c & 2) {
                const unsigned iv = *reinterpret_cast<const unsigned*>(lp + pos);
                DO1(iv & 0xFFFF); DO1(iv >> 16);
                pos += 2;
            }
            if (c & 1) DO1(lp[pos]);
        }
    }

    // ---- LIF scan (fp64, reference op order), h=0 -> handoff -> h=1
    const double A_M = 0.95, DTM = 0.05, A_S = 0.8;
    double* hand = (double*)wlds;              // reuse wlds: [2][128][4]
    const size_t obase = (size_t)o_blk * O_TILE + j;

    __syncthreads();   // all gathers done before reusing wlds
    if (h == 0) {
        double V0 = 0.0, I0 = 0.0, V1 = 0.0, I1 = 0.0;
#pragma unroll
        for (int tt = 0; tt < 10; ++tt) {
            V0 = A_M * V0 + DTM * I0;
            V1 = A_M * V1 + DTM * I1;
            float s0 = 0.0f, s1 = 0.0f;
            if (V0 >= 1.0) { s0 = 1.0f; V0 = 0.0; }
            if (V1 >= 1.0) { s1 = 1.0f; V1 = 0.0; }
            float* op = out + ((size_t)tt * BATCH + b) * DIM + obase;
            op[0] = s0; op[128] = s1;
            I0 = A_S * I0 + acc[tt][0];
            I1 = A_S * I1 + acc[tt][1];
        }
        double* hp = hand + ((size_t)bl * 128 + j) * 4;
        hp[0] = V0; hp[1] = I0; hp[2] = V1; hp[3] = I1;
    }
    __syncthreads();
    if (h == 1) {
        const double* hp = hand + ((size_t)bl * 128 + j) * 4;
        double V0 = hp[0], I0 = hp[1], V1 = hp[2], I1 = hp[3];
#pragma unroll
        for (int tt = 0; tt < 10; ++tt) {
            V0 = A_M * V0 + DTM * I0;
            V1 = A_M * V1 + DTM * I1;
            float s0 = 0.0f, s1 = 0.0f;
            if (V0 >= 1.0) { s0 = 1.0f; V0 = 0.0; }
            if (V1 >= 1.0) { s1 = 1.0f; V1 = 0.0; }
            float* op = out + ((size_t)(10 + tt) * BATCH + b) * DIM + obase;
            op[0] = s0; op[128] = s1;
            I0 = A_S * I0 + acc[tt][0];
            I1 = A_S * I1 + acc[tt][1];
        }
    }
}

extern "C" void kernel_launch(void* const* d_in, const int* in_sizes, int n_in,
                              void* d_out, int out_size, void* d_ws, size_t ws_size,
                              hipStream_t stream) {
    const float* x = (const float*)d_in[0];   // [20, 512, 2048] spikes
    const float* W = (const float*)d_in[1];   // [2048, 2048]
    float* out = (float*)d_out;               // [20, 512, 2048]

    const int grid = (BATCH / B_TILE) * (DIM / O_TILE);  // 256 * 8 = 2048
    snn_lif_kernel<<<grid, NT, 0, stream>>>(x, W, out);
}

// Round 4
// 710.894 us; speedup vs baseline: 3.2943x; 1.2794x over previous
//
#include <hip/hip_runtime.h>

// SpikingLinearLayer: 20-step LIF over [512 batch, 2048 out] driven by
// binary (10% dense) input spikes x[20,512,2048] through W[2048,2048].
//
//  - I-recurrence is linear & spike-independent -> all 20 GEMMs fused,
//    LIF V-scan stitched at the end (4 segments, LDS handoff).
//  - x is {0,1}: C[t,b,o] = sum of W rows at active i -> fp64 ADDS only
//    (fp64 required: binary spike output flips on ~1e-7 noise near
//    threshold; margin ~2.5e-8).
//  - R4: LDS was instruction-rate bound (ds_read2_b32 ~44B/cyc). Gather
//    now ds_read_b128 (~85B/cyc): thread owns 4 consecutive outputs.
//    Rows 16B-aligned via O_PAD=260; staging write conflicts killed by
//    k-row permutation R(k): row R holds k=4(R&15)+(R>>4) -> banks
//    (4a+ob)%32 = 2-way = free, with STATIC float4 component writes.
//    Lists/counts deleted: per-wave SGPR masks via __ballot + s_ff1
//    scalar iteration (SALU pipe is otherwise idle).

#define STEPS  20
#define BATCH  512
#define DIM    2048
#define B_TILE 2
#define O_TILE 256
#define NT     512
#define KT     64
#define NSLAB  (DIM / KT)     // 32
#define O_PAD  260            // floats per row = 1040 B (16B-aligned)

__global__ __launch_bounds__(NT, 4)
void snn_lif_kernel(const float* __restrict__ x,
                    const float* __restrict__ W,
                    float* __restrict__ out)
{
    __shared__ __align__(16) float wlds[KT * O_PAD];   // 66.6 KB

    const int tid  = threadIdx.x;
    const int lane = tid & 63;
    const int w    = tid >> 6;          // wave 0..7
    const int bl   = w & 1;             // batch-local
    const int tq   = w >> 1;            // step quarter: t in [5tq, 5tq+5)
    const int o_blk = blockIdx.x & 7;   // o fastest: W strip warm in L2
    const int b_blk = blockIdx.x >> 3;
    const int b = b_blk * B_TILE + bl;

    const int a    = tid & 15;          // k-quad within slab (owns k=4a..4a+3)
    const int obw  = tid >> 4;          // 0..31: o-row group for staging
    // mask bit L <-> LDS row L <-> k = 4*(L&15) + (L>>4)
    const int kperm = 4 * (lane & 15) + (lane >> 4);

    double acc[5][4];                   // C[5tq+tt][b][lane*4 + u]
#pragma unroll
    for (int tt = 0; tt < 5; ++tt)
#pragma unroll
        for (int u = 0; u < 4; ++u) acc[tt][u] = 0.0;

    const float* wbase = W + (size_t)(o_blk * O_TILE) * DIM;
    float4 wr[8];
    float  xr[5];

    {   // prefetch slab 0
#pragma unroll
        for (int it = 0; it < 8; ++it)
            wr[it] = *reinterpret_cast<const float4*>(
                wbase + (size_t)(obw + it * 32) * DIM + 4 * a);
#pragma unroll
        for (int m = 0; m < 5; ++m) {
            const int t = tq * 5 + m;
            xr[m] = x[((size_t)t * BATCH + b) * DIM + kperm];
        }
    }

    const char* gb = (const char*)wlds + (lane << 4);   // + r*1040 per entry

    for (int kt = 0; kt < NSLAB; ++kt) {
        __syncthreads();   // gathers of slab kt-1 done

        // ---- stage W slab from prefetched regs (permuted rows).
        // row a+16c holds k0+4a+c; bank = (4a+ob)%32 -> 2-way, free.
#pragma unroll
        for (int it = 0; it < 8; ++it) {
            const int o_off = obw + it * 32;
            wlds[(a +  0) * O_PAD + o_off] = wr[it].x;
            wlds[(a + 16) * O_PAD + o_off] = wr[it].y;
            wlds[(a + 32) * O_PAD + o_off] = wr[it].z;
            wlds[(a + 48) * O_PAD + o_off] = wr[it].w;
        }

        // ---- wave-uniform active masks from prefetched x (bit L = row L)
        unsigned long long mk[5];
#pragma unroll
        for (int m = 0; m < 5; ++m)
            mk[m] = __ballot(xr[m] != 0.0f);

        __syncthreads();   // wlds ready

        // ---- prefetch next slab (latency hidden behind the gather)
        if (kt + 1 < NSLAB) {
            const int k0 = (kt + 1) * KT;
#pragma unroll
            for (int it = 0; it < 8; ++it)
                wr[it] = *reinterpret_cast<const float4*>(
                    wbase + (size_t)(obw + it * 32) * DIM + k0 + 4 * a);
#pragma unroll
            for (int m = 0; m < 5; ++m) {
                const int t = tq * 5 + m;
                xr[m] = x[((size_t)t * BATCH + b) * DIM + k0 + kperm];
            }
        }

        // ---- sparse fp64 accumulate: s_ff1 scalar mask loop,
        //      one ds_read_b128 per active k (4 outputs/lane)
#pragma unroll
        for (int m = 0; m < 5; ++m) {
            unsigned long long msk = mk[m];
            while (msk) {
                const int r = __builtin_ctzll(msk);
                msk &= msk - 1;
                const float4 wv =
                    *reinterpret_cast<const float4*>(gb + r * (O_PAD * 4));
                acc[m][0] += (double)wv.x;
                acc[m][1] += (double)wv.y;
                acc[m][2] += (double)wv.z;
                acc[m][3] += (double)wv.w;
            }
        }
    }

    // ---- LIF scan (fp64, reference op order), 4 stitched segments
    const double A_M = 1.0 - 1.0 / 20.0;   // 0.95
    const double DTM = 1.0 / 20.0;         // 0.05
    const double A_S = 1.0 - 1.0 / 5.0;    // 0.8

    __syncthreads();                        // safe to reuse wlds
    double2* hand = reinterpret_cast<double2*>(wlds);  // [2][256] (V,I)
    const int hbase = bl * 256 + (lane << 2);
    const size_t obase = (size_t)o_blk * O_TILE + (lane << 2);

    for (int seg = 0; seg < 4; ++seg) {
        if (tq == seg) {
            double V[4], I[4];
            if (seg == 0) {
#pragma unroll
                for (int u = 0; u < 4; ++u) { V[u] = 0.0; I[u] = 0.0; }
            } else {
#pragma unroll
                for (int u = 0; u < 4; ++u) {
                    const double2 h = hand[hbase + u];
                    V[u] = h.x; I[u] = h.y;
                }
            }
#pragma unroll
            for (int tt = 0; tt < 5; ++tt) {
                const int t = seg * 5 + tt;
                float4 s;
                float* sp = &s.x;
#pragma unroll
                for (int u = 0; u < 4; ++u) {
                    V[u] = A_M * V[u] + DTM * I[u];
                    float sv = 0.0f;
                    if (V[u] >= 1.0) { sv = 1.0f; V[u] = 0.0; }
                    sp[u] = sv;
                    I[u] = A_S * I[u] + acc[tt][u];
                }
                *reinterpret_cast<float4*>(
                    out + ((size_t)t * BATCH + b) * DIM + obase) = s;
            }
            if (seg < 3) {
#pragma unroll
                for (int u = 0; u < 4; ++u)
                    hand[hbase + u] = make_double2(V[u], I[u]);
            }
        }
        __syncthreads();
    }
}

extern "C" void kernel_launch(void* const* d_in, const int* in_sizes, int n_in,
                              void* d_out, int out_size, void* d_ws, size_t ws_size,
                              hipStream_t stream) {
    const float* x = (const float*)d_in[0];   // [20, 512, 2048] spikes
    const float* W = (const float*)d_in[1];   // [2048, 2048]
    float* out = (float*)d_out;               // [20, 512, 2048]

    const int grid = (BATCH / B_TILE) * (DIM / O_TILE);  // 256 * 8 = 2048
    snn_lif_kernel<<<grid, NT, 0, stream>>>(x, W, out);
}

// Round 5
// 624.441 us; speedup vs baseline: 3.7503x; 1.1384x over previous
//
#include <hip/hip_runtime.h>
#include <stdint.h>

// SpikingLinearLayer: 20-step LIF over [512 batch, 2048 out] driven by
// binary (10% dense) input spikes x[20,512,2048] through W[2048,2048].
//
//  - I-recurrence is linear & spike-independent -> all 20 GEMMs fused,
//    LIF V-scan stitched at the end (4 segments, LDS handoff).
//  - x is {0,1}: C[t,b,o] = sum of W rows at active i -> fp64 ADDS only
//    (fp64 required: binary spike output flips on ~1e-7 noise near
//    threshold; margin ~2.5e-8).
//  - R4: ds_read_b128 gather (4 outputs/lane), SGPR masks + s_ff1 loop.
//  - R5: staging was 24% of the LDS pipe (65k ds_write_b32/CU) plus its
//    bank conflicts. Now: transpose W -> WT[k][o] in d_ws (~10us, every
//    launch since ws is re-poisoned), stage slabs via
//    global_load_lds_dwordx4 (1 KB row per wave-instr, DMA writes LDS,
//    no ds_write / no VGPR round-trip). Mask bit = LDS row = k (identity).

#define STEPS  20
#define BATCH  512
#define DIM    2048
#define B_TILE 2
#define O_TILE 256
#define NT     512
#define KT     64
#define NSLAB  (DIM / KT)     // 32
#define ROWB   1040           // LDS row stride bytes (16B-aligned, 1024 used)

#define GLOBAL_AS __attribute__((address_space(1)))
#define LDS_AS    __attribute__((address_space(3)))

__global__ __launch_bounds__(1024)
void transpose_kernel(const float* __restrict__ W, float* __restrict__ WT)
{
    __shared__ float tile[64][65];
    const int tx = threadIdx.x, ty = threadIdx.y;   // 64 x 16
    const int o0 = blockIdx.y * 64, k0 = blockIdx.x * 64;
#pragma unroll
    for (int i = 0; i < 64; i += 16)
        tile[ty + i][tx] = W[(size_t)(o0 + ty + i) * DIM + k0 + tx];
    __syncthreads();
#pragma unroll
    for (int i = 0; i < 64; i += 16)
        WT[(size_t)(k0 + ty + i) * DIM + o0 + tx] = tile[tx][ty + i];
}

__global__ __launch_bounds__(NT, 4)
void snn_lif_kernel(const float* __restrict__ x,
                    const float* __restrict__ WT,
                    float* __restrict__ out)
{
    __shared__ __align__(16) float wlds[(KT * ROWB) / 4];   // 66.56 KB

    const int tid  = threadIdx.x;
    const int lane = tid & 63;
    const int w    = tid >> 6;          // wave 0..7
    const int bl   = w & 1;             // batch-local
    const int tq   = w >> 1;            // step quarter: t in [5tq, 5tq+5)
    const int o_blk = blockIdx.x & 7;   // o fastest: W strip warm in L2
    const int b_blk = blockIdx.x >> 3;
    const int b  = b_blk * B_TILE + bl;
    const int o0 = o_blk * O_TILE;

    double acc[5][4];                   // C[5tq+tt][b][lane*4 + u]
#pragma unroll
    for (int tt = 0; tt < 5; ++tt)
#pragma unroll
        for (int u = 0; u < 4; ++u) acc[tt][u] = 0.0;

    float xr[5];                        // prefetched x for current slab
#pragma unroll
    for (int m = 0; m < 5; ++m)
        xr[m] = x[((size_t)(tq * 5 + m) * BATCH + b) * DIM + lane];

    const char*   gb   = (const char*)wlds + (lane << 4);
    LDS_AS char*  ldsb = (LDS_AS char*)wlds;
    const float*  wsrc = WT + o0 + (lane << 2);   // lane's 16B within a row

    for (int kt = 0; kt < NSLAB; ++kt) {
        const int k0 = kt * KT;
        __syncthreads();   // gathers of slab kt-1 done; LDS reusable

        // ---- DMA-stage slab kt: wave w stages rows {w + 8*it}.
        // dest = uniform row base + lane*16 (HW); src = WT row, per-lane.
#pragma unroll
        for (int it = 0; it < 8; ++it) {
            const int r = w + it * 8;
            __builtin_amdgcn_global_load_lds(
                (const GLOBAL_AS void*)(wsrc + (size_t)(k0 + r) * DIM),
                (LDS_AS void*)(ldsb + r * ROWB), 16, 0, 0);
        }

        // ---- wave-uniform active masks (bit L = row L = k0+L)
        unsigned long long mk[5];
#pragma unroll
        for (int m = 0; m < 5; ++m)
            mk[m] = __ballot(xr[m] != 0.0f);

        __syncthreads();   // compiler drains vmcnt(0): DMA visible to all

        // ---- prefetch x for next slab (in flight behind the gather)
        if (kt + 1 < NSLAB) {
            const int k1 = k0 + KT;
#pragma unroll
            for (int m = 0; m < 5; ++m)
                xr[m] = x[((size_t)(tq * 5 + m) * BATCH + b) * DIM + k1 + lane];
        }

        // ---- sparse fp64 accumulate: s_ff1 scalar mask loop,
        //      one ds_read_b128 per active k (4 outputs/lane)
#pragma unroll
        for (int m = 0; m < 5; ++m) {
            unsigned long long msk = mk[m];
            while (msk) {
                const int r = __builtin_ctzll(msk);
                msk &= msk - 1;
                const float4 wv =
                    *reinterpret_cast<const float4*>(gb + r * ROWB);
                acc[m][0] += (double)wv.x;
                acc[m][1] += (double)wv.y;
                acc[m][2] += (double)wv.z;
                acc[m][3] += (double)wv.w;
            }
        }
    }

    // ---- LIF scan (fp64, reference op order), 4 stitched segments
    const double A_M = 1.0 - 1.0 / 20.0;   // 0.95
    const double DTM = 1.0 / 20.0;         // 0.05
    const double A_S = 1.0 - 1.0 / 5.0;    // 0.8

    __syncthreads();                        // safe to reuse wlds
    double2* hand = reinterpret_cast<double2*>(wlds);  // [2][256] (V,I)
    const int hbase = bl * 256 + (lane << 2);
    const size_t obase = (size_t)o0 + (lane << 2);

    for (int seg = 0; seg < 4; ++seg) {
        if (tq == seg) {
            double V[4], I[4];
            if (seg == 0) {
#pragma unroll
                for (int u = 0; u < 4; ++u) { V[u] = 0.0; I[u] = 0.0; }
            } else {
#pragma unroll
                for (int u = 0; u < 4; ++u) {
                    const double2 h = hand[hbase + u];
                    V[u] = h.x; I[u] = h.y;
                }
            }
#pragma unroll
            for (int tt = 0; tt < 5; ++tt) {
                const int t = seg * 5 + tt;
                float4 s;
                float* sp = &s.x;
#pragma unroll
                for (int u = 0; u < 4; ++u) {
                    V[u] = A_M * V[u] + DTM * I[u];
                    float sv = 0.0f;
                    if (V[u] >= 1.0) { sv = 1.0f; V[u] = 0.0; }
                    sp[u] = sv;
                    I[u] = A_S * I[u] + acc[tt][u];
                }
                *reinterpret_cast<float4*>(
                    out + ((size_t)t * BATCH + b) * DIM + obase) = s;
            }
            if (seg < 3) {
#pragma unroll
                for (int u = 0; u < 4; ++u)
                    hand[hbase + u] = make_double2(V[u], I[u]);
            }
        }
        __syncthreads();
    }
}

extern "C" void kernel_launch(void* const* d_in, const int* in_sizes, int n_in,
                              void* d_out, int out_size, void* d_ws, size_t ws_size,
                              hipStream_t stream) {
    const float* x = (const float*)d_in[0];   // [20, 512, 2048] spikes
    const float* W = (const float*)d_in[1];   // [2048, 2048]
    float* out = (float*)d_out;               // [20, 512, 2048]
    float* WT  = (float*)d_ws;                // [2048, 2048] transposed W

    dim3 tb(64, 16);
    dim3 tg(DIM / 64, DIM / 64);
    transpose_kernel<<<tg, tb, 0, stream>>>(W, WT);

    const int grid = (BATCH / B_TILE) * (DIM / O_TILE);  // 256 * 8 = 2048
    snn_lif_kernel<<<grid, NT, 0, stream>>>(x, WT, out);
}